// Round 11
// baseline (249.918 us; speedup 1.0000x reference)
//
#include <hip/hip_runtime.h>
#include <math.h>

typedef __attribute__((ext_vector_type(8))) short b8;
typedef __attribute__((ext_vector_type(4))) float f4;
typedef __attribute__((ext_vector_type(4))) int i4;
typedef float f4u __attribute__((ext_vector_type(4), aligned(4)));
typedef _Float16 h8 __attribute__((ext_vector_type(8)));
typedef _Float16 h2 __attribute__((ext_vector_type(2)));

// ---------------- fallback (R7) ws layout (float offsets) ------------------
#define WS_OFFS   0
#define WS_GY0    294912
#define WS_GY1    884736
#define WS_IP     1474560
#define WS_AFRAG  1769472
#define WS_BFOLD  2064384
#define WS_K1WH   294912
#define WS_K1WL   331776

// ---------------- big-ws (XT) layout (float offsets) -----------------------
#define XT2   0                     // f16[4*4096*256] = 2097152 floats
#define OF2   2097152               // 294912 (fp32 accumulated offsets)
#define DW2   2392064               // uint4[147456] (half2-dup weights)
#define DP2   2981888               // int4[147456] (corner positions)
#define AF2   3571712               // f16[589824]
#define BF2   3866624               // 256
#define WH2   2392064               // overlay in DW2
#define WL2   2428928
#define XT_TOTAL_BYTES (3866880u * 4u)

__device__ inline ushort f2bf(float f) {
  uint u = __float_as_uint(f);
  return (ushort)((u + 0x7FFFu + ((u >> 16) & 1u)) >> 16);
}
__device__ inline h2 u2h2(uint u) { union { uint u; h2 h; } x; x.u = u; return x.h; }
__device__ inline uint h22u(h2 h) { union { uint u; h2 h; } x; x.h = h; return x.u; }
__device__ inline uint duph(float f) {
  union { _Float16 h; ushort u; } x; x.h = (_Float16)f;
  return ((uint)x.u << 16) | x.u;
}

// ---------------------------------------------------------------------------
// prep (R10 verbatim)
// ---------------------------------------------------------------------------
__global__ __launch_bounds__(256) void prep_k(
    const float* __restrict__ w, const float* __restrict__ wof,
    const float* __restrict__ bias,
    const float* __restrict__ gamma, const float* __restrict__ beta,
    const float* __restrict__ mean, const float* __restrict__ var,
    float* __restrict__ ws, int AF, int BF, int WH, int WL, int mode) {
  const int tid = blockIdx.x * 256 + threadIdx.x;
  const int l  = tid & 63;
  const int ot = (tid >> 6) & 15;
  const int f  = tid >> 10;
  const int o  = (ot << 4) + (l & 15);
  const float inv = gamma[o] * rsqrtf(var[o] + 1e-5f);
  if (mode == 0) {
    const int cg = f / 9;
    const int kk = f - cg * 9;
    const int cb = (cg << 5) + ((l >> 4) << 3);
    b8 pk;
#pragma unroll
    for (int j = 0; j < 8; ++j)
      pk[j] = (short)f2bf(w[((o << 8) + cb + j) * 9 + kk] * inv);
    *(b8*)((short*)(ws + AF) + tid * 8) = pk;
  } else {
    const int s  = f & 1;
    const int g  = f >> 1;
    const int cw = g / 9;
    const int kk = g - cw * 9;
    const int cb = (cw << 6) + (s << 5) + ((l >> 4) << 3);
    h8 pk;
#pragma unroll
    for (int j = 0; j < 8; ++j)
      pk[j] = (_Float16)(w[((o << 8) + cb + j) * 9 + kk] * inv);
    *(h8*)((_Float16*)(ws + AF) + tid * 8) = pk;
    ((f4*)(ws + OF2))[tid] = f4{0.f, 0.f, 0.f, 0.f};
  }
  if (tid < 256) {
    const float iv = gamma[tid] * rsqrtf(var[tid] + 1e-5f);
    ws[BF + tid] = bias[tid] * iv + beta[tid] - mean[tid] * iv;
  }
  if (tid < 9216) {
    const int l2  = tid & 63;
    const int mt  = (tid >> 6) & 1;
    const int i2  = tid >> 7;
    const int cg2 = i2 / 9;
    const int kk2 = i2 - cg2 * 9;
    const int oc  = (mt << 4) + (l2 & 15);
    const int cb2 = (cg2 << 5) + ((l2 >> 4) << 3);
    b8 ph, pl;
#pragma unroll
    for (int j = 0; j < 8; ++j) {
      const float v = (oc < 18) ? wof[((oc << 8) + cb2 + j) * 9 + kk2] : 0.f;
      const ushort h = f2bf(v);
      const float hf = __uint_as_float((uint)h << 16);
      ph[j] = (short)h;
      pl[j] = (short)f2bf(v - hf);
    }
    *(b8*)((short*)(ws + WH) + tid * 8) = ph;
    *(b8*)((short*)(ws + WL) + tid * 8) = pl;
  }
}

// ---------------------------------------------------------------------------
// transpose (R10 verbatim)
// ---------------------------------------------------------------------------
__global__ __launch_bounds__(256) void transpose_k(
    const float* __restrict__ x, float* __restrict__ ws) {
  const int id  = blockIdx.x * 256 + threadIdx.x;
  const int p   = id & 4095;
  const int cg8 = (id >> 12) & 31;
  const int b   = id >> 17;
  const float* xp = x + (((long)(b * 256 + cg8 * 8)) << 12) + p;
  _Float16* xt = (_Float16*)(ws + XT2);
  h8 pk;
#pragma unroll
  for (int j = 0; j < 8; ++j) pk[j] = (_Float16)xp[(long)j << 12];
  *(h8*)(xt + ((((long)(b << 12) + p)) << 8) + (cg8 << 3)) = pk;
}

// ---------------------------------------------------------------------------
// K1 big path (R10 verbatim): offset conv K-split x4, atomics into OF2.
// ---------------------------------------------------------------------------
__global__ __launch_bounds__(256, 4) void offset_part_k(
    const float* __restrict__ x, float* __restrict__ ws) {
  __shared__ __align__(16) ushort Xh[3][66][40];
  __shared__ __align__(16) ushort Xl[3][66][40];
  const int bid = blockIdx.x;
  const int q   = bid >> 8;
  const int b   = (bid >> 6) & 3;
  const int ho  = bid & 63;
  const int t   = threadIdx.x;
  const int l   = t & 63;
  const int wv  = t >> 6;
  const short* afh = (const short*)(ws + WH2);
  const short* afl = (const short*)(ws + WL2);

  for (int u = t; u < 240; u += 256) {
    const int row = u / 80, rem = u % 80;
    const int col = (rem >= 40) ? 65 : 0;
    const int c   = rem % 40;
    Xh[row][col][c] = 0;
    Xl[row][col][c] = 0;
  }

  f4 acc[2];
  acc[0] = f4{0.f, 0.f, 0.f, 0.f};
  acc[1] = f4{0.f, 0.f, 0.f, 0.f};

  const int cidx = t >> 3;
  const int j8   = t & 7;
  const float* xc = x + ((long)b << 20) + ((long)cidx << 12);
  const int col = (wv << 4) + (l & 15);
  const int qc  = (l >> 4) << 3;

  for (int it = 0; it < 2; ++it) {
    const int cg = (q << 1) + it;
    __syncthreads();
    const float* xg = xc + ((long)(cg << 5) << 12);
#pragma unroll
    for (int rep = 0; rep < 6; ++rep) {
      const int fi   = (rep << 3) + j8;
      const int row  = fi >> 4;
      const int colf = (fi & 15) << 2;
      const int y = ho - 1 + row;
      f4u v = {0.f, 0.f, 0.f, 0.f};
      if (y >= 0 && y <= 63) v = *(const f4u*)(xg + (y << 6) + colf);
#pragma unroll
      for (int qq = 0; qq < 4; ++qq) {
        const ushort h = f2bf(v[qq]);
        const float hf = __uint_as_float((uint)h << 16);
        Xh[row][colf + 1 + qq][cidx] = h;
        Xl[row][colf + 1 + qq][cidx] = f2bf(v[qq] - hf);
      }
    }
    __syncthreads();
#pragma unroll
    for (int kk = 0; kk < 9; ++kk) {
      const int ky = kk / 3, kx = kk - ky * 3;
      const int i  = cg * 9 + kk;
      const b8 ah0 = *(const b8*)(afh + ((((i << 1) + 0) << 6) + l) * 8);
      const b8 ah1 = *(const b8*)(afh + ((((i << 1) + 1) << 6) + l) * 8);
      const b8 al0 = *(const b8*)(afl + ((((i << 1) + 0) << 6) + l) * 8);
      const b8 al1 = *(const b8*)(afl + ((((i << 1) + 1) << 6) + l) * 8);
      const b8 bh = *(const b8*)&Xh[ky][col + kx][qc];
      const b8 bl = *(const b8*)&Xl[ky][col + kx][qc];
      acc[0] = __builtin_amdgcn_mfma_f32_16x16x32_bf16(ah0, bh, acc[0], 0, 0, 0);
      acc[0] = __builtin_amdgcn_mfma_f32_16x16x32_bf16(ah0, bl, acc[0], 0, 0, 0);
      acc[0] = __builtin_amdgcn_mfma_f32_16x16x32_bf16(al0, bh, acc[0], 0, 0, 0);
      acc[1] = __builtin_amdgcn_mfma_f32_16x16x32_bf16(ah1, bh, acc[1], 0, 0, 0);
      acc[1] = __builtin_amdgcn_mfma_f32_16x16x32_bf16(ah1, bl, acc[1], 0, 0, 0);
      acc[1] = __builtin_amdgcn_mfma_f32_16x16x32_bf16(al1, bh, acc[1], 0, 0, 0);
    }
  }

  const int wo = col;
  const int q4 = (l >> 4) << 2;
#pragma unroll
  for (int mt = 0; mt < 2; ++mt)
#pragma unroll
    for (int r = 0; r < 4; ++r) {
      const int oc = (mt << 4) + q4 + r;
      if (oc < 18)
        atomicAdd(&ws[OF2 + ((b * 18 + oc) << 12) + (ho << 6) + wo],
                  acc[mt][r]);
    }
}

// ---------------------------------------------------------------------------
// descriptor math + K2 XT (R10 verbatim)
// ---------------------------------------------------------------------------
struct DescOut {
  float w00, w01, w10, w11;
  int y0c, y1c, x0c, x1c;
};
__device__ inline DescOut desc_math(const float* ws, const float* bof,
                                    int OFFS, int d) {
  const int k  = d >> 14;
  const int n  = d & 16383;
  const int b  = n >> 12;
  const int sp = n & 4095;
  const int ho = sp >> 6, wo = sp & 63;
  const int ky = k / 3, kx = k - ky * 3;
  const float dy = ws[OFFS + ((b * 18 + (k << 1)) << 12) + sp] + bof[k << 1];
  const float dx = ws[OFFS + ((b * 18 + (k << 1) + 1) << 12) + sp] + bof[(k << 1) + 1];
  const float py = (float)(ho - 1 + ky) + dy;
  const float px = (float)(wo - 1 + kx) + dx;
  const float y0f = floorf(py), x0f = floorf(px);
  const float ly = py - y0f, lx = px - x0f;
  const int y0 = (int)y0f, x0 = (int)x0f;
  const int y1 = y0 + 1, x1 = x0 + 1;
  const float vy0 = (y0 >= 0 && y0 < 64) ? 1.f : 0.f;
  const float vy1 = (y1 >= 0 && y1 < 64) ? 1.f : 0.f;
  const float vx0 = (x0 >= 0 && x0 < 64) ? 1.f : 0.f;
  const float vx1 = (x1 >= 0 && x1 < 64) ? 1.f : 0.f;
  DescOut o;
  o.y0c = min(max(y0, 0), 63); o.y1c = min(max(y1, 0), 63);
  o.x0c = min(max(x0, 0), 63); o.x1c = min(max(x1, 0), 63);
  o.w00 = (1.f - ly) * (1.f - lx) * vy0 * vx0;
  o.w01 = (1.f - ly) * lx * vy0 * vx1;
  o.w10 = ly * (1.f - lx) * vy1 * vx0;
  o.w11 = ly * lx * vy1 * vx1;
  return o;
}

__global__ __launch_bounds__(256) void make_desc_xt(
    const float* __restrict__ bof, float* __restrict__ ws) {
  const int d = blockIdx.x * 256 + threadIdx.x;
  DescOut q = desc_math(ws, bof, OF2, d);
  uint4 wv;
  wv.x = duph(q.w00); wv.y = duph(q.w01);
  wv.z = duph(q.w10); wv.w = duph(q.w11);
  int4 pv;
  pv.x = (q.y0c << 6) + q.x0c;
  pv.y = (q.y0c << 6) + q.x1c;
  pv.z = (q.y1c << 6) + q.x0c;
  pv.w = (q.y1c << 6) + q.x1c;
  ((uint4*)(ws + DW2))[d] = wv;
  ((int4*)(ws + DP2))[d] = pv;
}

// ---------------------------------------------------------------------------
// K3: wave-autonomous f16 MFMA GEMM — NO barrier in the K-loop.
// Grid 256 x 512 thr. Block tile 256o x 64n; wave = 64o x 32n (2 samples/lane,
// lane l: samples nw+(l&15), +16; k-quad l>>4). B-fragments built in REGISTERS
// (gather 16B/corner in B-operand layout, pk_fma combine) — no Bs LDS, no
// __syncthreads after the one-time desc fill -> waves slip freely, compiler
// emits fine-grained vmcnt per wave.
// ---------------------------------------------------------------------------
__global__ __launch_bounds__(512) void deform_gemm_wf(
    const float* __restrict__ ws, float* __restrict__ out) {
  __shared__ uint4 dW[576];   // [kk][64 samples] half2-dup weights
  __shared__ int4  dP[576];   // corner positions

  const int t     = threadIdx.x;
  const int bid   = blockIdx.x;
  const int xcd   = bid & 7;
  const int batch = xcd >> 1;
  const int half  = xcd & 1;
  const int slot  = bid >> 3;                 // 0..31
  const int sp0   = (half << 11) + (slot << 6);
  const int nd0   = (batch << 12) + sp0;
  const int l     = t & 63;
  const int wv    = t >> 6;                   // 0..7

  const uint* xtu = (const uint*)(ws + XT2) + ((long)batch << 19);
  const _Float16* af = (const _Float16*)(ws + AF2);

  // one-time descriptor LDS fill (the only barrier)
  for (int u = t; u < 576; u += 512) {
    const int kk = u >> 6, s = u & 63;
    const int dg = (kk << 14) + nd0 + s;
    dW[u] = ((const uint4*)(ws + DW2))[dg];
    dP[u] = ((const int4*)(ws + DP2))[dg];
  }
  __syncthreads();

  const int otb = (wv & 3) << 2;              // wave o-slice: 4 o-tiles
  const int nw  = (wv >> 2) << 5;             // wave n base (0/32)
  const int sn0 = nw + (l & 15);
  const int sn1 = sn0 + 16;
  const int q4u = (l >> 4) << 2;              // k-quad offset in uints

  f4 acc[4][2];
#pragma unroll
  for (int m = 0; m < 4; ++m) {
    acc[m][0] = f4{0.f, 0.f, 0.f, 0.f};
    acc[m][1] = f4{0.f, 0.f, 0.f, 0.f};
  }

  uint4 wd0, wd1, wn0, wn1;
  int4  pd0, pd1, pn0, pn1;
  uint4 G0[8], G1[8];                         // corner regs, s=0 / s=1
  h8 A0[4], A1[4];

#define WRDD(KK_, W0_, W1_, P0_, P1_) do {                                   \
    const int u_ = ((KK_) << 6);                                             \
    W0_ = dW[u_ + sn0]; P0_ = dP[u_ + sn0];                                  \
    W1_ = dW[u_ + sn1]; P1_ = dP[u_ + sn1]; } while (0)

#define WGATH(G_, P0_, P1_, CW_, S_) do {                                    \
    const int ba_ = ((CW_) << 5) + ((S_) << 4) + q4u;                        \
    G_[0] = *(const uint4*)(xtu + ((P0_).x << 7) + ba_);                     \
    G_[1] = *(const uint4*)(xtu + ((P0_).y << 7) + ba_);                     \
    G_[2] = *(const uint4*)(xtu + ((P0_).z << 7) + ba_);                     \
    G_[3] = *(const uint4*)(xtu + ((P0_).w << 7) + ba_);                     \
    G_[4] = *(const uint4*)(xtu + ((P1_).x << 7) + ba_);                     \
    G_[5] = *(const uint4*)(xtu + ((P1_).y << 7) + ba_);                     \
    G_[6] = *(const uint4*)(xtu + ((P1_).z << 7) + ba_);                     \
    G_[7] = *(const uint4*)(xtu + ((P1_).w << 7) + ba_); } while (0)

#define WLOADA(F_, D_) do {                                                  \
    _Pragma("unroll")                                                        \
    for (int m = 0; m < 4; ++m)                                              \
      D_[m] = *(const h8*)(af + (((((F_) << 4) + otb + m) << 6) + l) * 8);   \
  } while (0)

#define WCOMB1(G_, O_, WD_, B_) do {                                         \
    const h2 w0_ = u2h2((WD_).x), w1_ = u2h2((WD_).y);                       \
    const h2 w2_ = u2h2((WD_).z), w3_ = u2h2((WD_).w);                       \
    B_.x = h22u(u2h2(G_[(O_)+0].x) * w0_ + u2h2(G_[(O_)+1].x) * w1_ +        \
                u2h2(G_[(O_)+2].x) * w2_ + u2h2(G_[(O_)+3].x) * w3_);        \
    B_.y = h22u(u2h2(G_[(O_)+0].y) * w0_ + u2h2(G_[(O_)+1].y) * w1_ +        \
                u2h2(G_[(O_)+2].y) * w2_ + u2h2(G_[(O_)+3].y) * w3_);        \
    B_.z = h22u(u2h2(G_[(O_)+0].z) * w0_ + u2h2(G_[(O_)+1].z) * w1_ +        \
                u2h2(G_[(O_)+2].z) * w2_ + u2h2(G_[(O_)+3].z) * w3_);        \
    B_.w = h22u(u2h2(G_[(O_)+0].w) * w0_ + u2h2(G_[(O_)+1].w) * w1_ +        \
                u2h2(G_[(O_)+2].w) * w2_ + u2h2(G_[(O_)+3].w) * w3_);        \
  } while (0)

#define WMFMA(G_, A_) do {                                                   \
    uint4 bu0_, bu1_;                                                        \
    WCOMB1(G_, 0, wd0, bu0_);                                                \
    WCOMB1(G_, 4, wd1, bu1_);                                                \
    const h8 b0_ = *(const h8*)&bu0_;                                        \
    const h8 b1_ = *(const h8*)&bu1_;                                        \
    _Pragma("unroll")                                                        \
    for (int m = 0; m < 4; ++m) {                                            \
      acc[m][0] = __builtin_amdgcn_mfma_f32_16x16x32_f16(                    \
          A_[m], b0_, acc[m][0], 0, 0, 0);                                   \
      acc[m][1] = __builtin_amdgcn_mfma_f32_16x16x32_f16(                    \
          A_[m], b1_, acc[m][1], 0, 0, 0);                                   \
    }                                                                        \
  } while (0)

  // prologue: i=0 (cw0,kk0,s0)
  WRDD(0, wd0, wd1, pd0, pd1);
  WGATH(G0, pd0, pd1, 0, 0);
  WLOADA(0, A0);

  int kkc = 0, cwc = 0;
  for (int i = 0; i < 36; ++i) {
    int kkn = kkc + 1, cwn = cwc;
    if (kkn == 9) { kkn = 0; cwn++; }
    if (i < 35) WRDD(kkn, wn0, wn1, pn0, pn1);
    // gather + A for (i, s=1)
    WGATH(G1, pd0, pd1, cwc, 1);
    WLOADA((i << 1) + 1, A1);
    // compute s=0 half (corners gathered one half-iter ago)
    WMFMA(G0, A0);
    // gather + A for (i+1, s=0) with NEXT desc positions
    if (i < 35) {
      WGATH(G0, pn0, pn1, cwn, 0);
      WLOADA((i << 1) + 2, A0);
    }
    // compute s=1 half (still uses current weights wd0/wd1)
    WMFMA(G1, A1);
    wd0 = wn0; wd1 = wn1; pd0 = pn0; pd1 = pn1;
    kkc = kkn; cwc = cwn;
  }

  const float* bfold = ws + BF2;
  const int q4 = (l >> 4) << 2;
  const int ow = (wv & 3) << 6;
#pragma unroll
  for (int m = 0; m < 4; ++m) {
    const int ob = ow + (m << 4) + q4;
    const f4 bf = *(const f4*)&bfold[ob];
#pragma unroll
    for (int nt = 0; nt < 2; ++nt) {
      const int sp = sp0 + nw + (nt << 4) + (l & 15);
#pragma unroll
      for (int r = 0; r < 4; ++r) {
        out[(((batch << 8) + ob + r) << 12) + sp] =
            fmaxf(acc[m][nt][r] + bf[r], 0.f);
      }
    }
  }
}

// ---------------------------------------------------------------------------
extern "C" void kernel_launch(void* const* d_in, const int* in_sizes, int n_in,
                              void* d_out, int out_size, void* d_ws, size_t ws_size,
                              hipStream_t stream) {
  const float* x     = (const float*)d_in[0];
  const float* wof   = (const float*)d_in[1];
  const float* bof   = (const float*)d_in[2];
  const float* w     = (const float*)d_in[3];
  const float* bias  = (const float*)d_in[4];
  const float* gamma = (const float*)d_in[5];
  const float* beta  = (const float*)d_in[6];
  const float* mean  = (const float*)d_in[7];
  const float* var   = (const float*)d_in[8];
  float* out = (float*)d_out;
  float* ws  = (float*)d_ws;

  hipLaunchKernelGGL(prep_k, dim3(288), dim3(256), 0, stream,
                     w, wof, bias, gamma, beta, mean, var, ws,
                     AF2, BF2, WH2, WL2, 1);
  hipLaunchKernelGGL(transpose_k, dim3(2048), dim3(256), 0, stream, x, ws);
  hipLaunchKernelGGL(offset_part_k, dim3(1024), dim3(256), 0, stream, x, ws);
  hipLaunchKernelGGL(make_desc_xt, dim3(576), dim3(256), 0, stream, bof, ws);
  hipLaunchKernelGGL(deform_gemm_wf, dim3(256), dim3(512), 0, stream,
                     ws, out);
}

// Round 12
// 161.708 us; speedup vs baseline: 1.5455x; 1.5455x over previous
//
#include <hip/hip_runtime.h>
#include <math.h>

typedef __attribute__((ext_vector_type(8))) short b8;
typedef __attribute__((ext_vector_type(4))) float f4;
typedef float f4u __attribute__((ext_vector_type(4), aligned(4)));
typedef _Float16 h8 __attribute__((ext_vector_type(8)));
typedef _Float16 h2 __attribute__((ext_vector_type(2)));

// ---------------- big-ws (XT) layout (float offsets) -----------------------
#define XT2   0                     // f16[4*4096*256] = 2097152 floats
#define OF2   2097152               // 294912 (fp32 accumulated offsets)
#define DW2   2392064               // uint4[147456] (half2-dup weights)
#define DP2   2981888               // int4[147456] (corner positions)
#define AF2   3571712               // f16[589824]
#define BF2   3866624               // 256
#define WH2   2392064               // overlay in DW2
#define WL2   2428928

__device__ inline ushort f2bf(float f) {
  uint u = __float_as_uint(f);
  return (ushort)((u + 0x7FFFu + ((u >> 16) & 1u)) >> 16);
}
__device__ inline h2 u2h2(uint u) { union { uint u; h2 h; } x; x.u = u; return x.h; }
__device__ inline uint h22u(h2 h) { union { uint u; h2 h; } x; x.h = h; return x.u; }
__device__ inline uint duph(float f) {
  union { _Float16 h; ushort u; } x; x.h = (_Float16)f;
  return ((uint)x.u << 16) | x.u;
}

// ---------------------------------------------------------------------------
// prep (R10 verbatim, big path only): f16 A-frags in (cw64,kk,s) order,
// zero OF2, folded bias, K1 bf16-split offset weights.
// ---------------------------------------------------------------------------
__global__ __launch_bounds__(256) void prep_k(
    const float* __restrict__ w, const float* __restrict__ wof,
    const float* __restrict__ bias,
    const float* __restrict__ gamma, const float* __restrict__ beta,
    const float* __restrict__ mean, const float* __restrict__ var,
    float* __restrict__ ws) {
  const int tid = blockIdx.x * 256 + threadIdx.x;
  const int l  = tid & 63;
  const int ot = (tid >> 6) & 15;
  const int f  = tid >> 10;
  const int o  = (ot << 4) + (l & 15);
  const float inv = gamma[o] * rsqrtf(var[o] + 1e-5f);
  {
    const int s  = f & 1;
    const int g  = f >> 1;
    const int cw = g / 9;
    const int kk = g - cw * 9;
    const int cb = (cw << 6) + (s << 5) + ((l >> 4) << 3);
    h8 pk;
#pragma unroll
    for (int j = 0; j < 8; ++j)
      pk[j] = (_Float16)(w[((o << 8) + cb + j) * 9 + kk] * inv);
    *(h8*)((_Float16*)(ws + AF2) + tid * 8) = pk;
    ((f4*)(ws + OF2))[tid] = f4{0.f, 0.f, 0.f, 0.f};
  }
  if (tid < 256) {
    const float iv = gamma[tid] * rsqrtf(var[tid] + 1e-5f);
    ws[BF2 + tid] = bias[tid] * iv + beta[tid] - mean[tid] * iv;
  }
  if (tid < 9216) {
    const int l2  = tid & 63;
    const int mt  = (tid >> 6) & 1;
    const int i2  = tid >> 7;
    const int cg2 = i2 / 9;
    const int kk2 = i2 - cg2 * 9;
    const int oc  = (mt << 4) + (l2 & 15);
    const int cb2 = (cg2 << 5) + ((l2 >> 4) << 3);
    b8 ph, pl;
#pragma unroll
    for (int j = 0; j < 8; ++j) {
      const float v = (oc < 18) ? wof[((oc << 8) + cb2 + j) * 9 + kk2] : 0.f;
      const ushort h = f2bf(v);
      const float hf = __uint_as_float((uint)h << 16);
      ph[j] = (short)h;
      pl[j] = (short)f2bf(v - hf);
    }
    *(b8*)((short*)(ws + WH2) + tid * 8) = ph;
    *(b8*)((short*)(ws + WL2) + tid * 8) = pl;
  }
}

// ---------------------------------------------------------------------------
// transpose (R10 verbatim): x (B,C,H,W) fp32 -> xt (B,P,C) f16.
// ---------------------------------------------------------------------------
__global__ __launch_bounds__(256) void transpose_k(
    const float* __restrict__ x, float* __restrict__ ws) {
  const int id  = blockIdx.x * 256 + threadIdx.x;
  const int p   = id & 4095;
  const int cg8 = (id >> 12) & 31;
  const int b   = id >> 17;
  const float* xp = x + (((long)(b * 256 + cg8 * 8)) << 12) + p;
  _Float16* xt = (_Float16*)(ws + XT2);
  h8 pk;
#pragma unroll
  for (int j = 0; j < 8; ++j) pk[j] = (_Float16)xp[(long)j << 12];
  *(h8*)(xt + ((((long)(b << 12) + p)) << 8) + (cg8 << 3)) = pk;
}

// ---------------------------------------------------------------------------
// K1 (R10 verbatim): offset conv K-split x4, atomics into OF2.
// ---------------------------------------------------------------------------
__global__ __launch_bounds__(256, 4) void offset_part_k(
    const float* __restrict__ x, float* __restrict__ ws) {
  __shared__ __align__(16) ushort Xh[3][66][40];
  __shared__ __align__(16) ushort Xl[3][66][40];
  const int bid = blockIdx.x;
  const int q   = bid >> 8;
  const int b   = (bid >> 6) & 3;
  const int ho  = bid & 63;
  const int t   = threadIdx.x;
  const int l   = t & 63;
  const int wv  = t >> 6;
  const short* afh = (const short*)(ws + WH2);
  const short* afl = (const short*)(ws + WL2);

  for (int u = t; u < 240; u += 256) {
    const int row = u / 80, rem = u % 80;
    const int col = (rem >= 40) ? 65 : 0;
    const int c   = rem % 40;
    Xh[row][col][c] = 0;
    Xl[row][col][c] = 0;
  }

  f4 acc[2];
  acc[0] = f4{0.f, 0.f, 0.f, 0.f};
  acc[1] = f4{0.f, 0.f, 0.f, 0.f};

  const int cidx = t >> 3;
  const int j8   = t & 7;
  const float* xc = x + ((long)b << 20) + ((long)cidx << 12);
  const int col = (wv << 4) + (l & 15);
  const int qc  = (l >> 4) << 3;

  for (int it = 0; it < 2; ++it) {
    const int cg = (q << 1) + it;
    __syncthreads();
    const float* xg = xc + ((long)(cg << 5) << 12);
#pragma unroll
    for (int rep = 0; rep < 6; ++rep) {
      const int fi   = (rep << 3) + j8;
      const int row  = fi >> 4;
      const int colf = (fi & 15) << 2;
      const int y = ho - 1 + row;
      f4u v = {0.f, 0.f, 0.f, 0.f};
      if (y >= 0 && y <= 63) v = *(const f4u*)(xg + (y << 6) + colf);
#pragma unroll
      for (int qq = 0; qq < 4; ++qq) {
        const ushort h = f2bf(v[qq]);
        const float hf = __uint_as_float((uint)h << 16);
        Xh[row][colf + 1 + qq][cidx] = h;
        Xl[row][colf + 1 + qq][cidx] = f2bf(v[qq] - hf);
      }
    }
    __syncthreads();
#pragma unroll
    for (int kk = 0; kk < 9; ++kk) {
      const int ky = kk / 3, kx = kk - ky * 3;
      const int i  = cg * 9 + kk;
      const b8 ah0 = *(const b8*)(afh + ((((i << 1) + 0) << 6) + l) * 8);
      const b8 ah1 = *(const b8*)(afh + ((((i << 1) + 1) << 6) + l) * 8);
      const b8 al0 = *(const b8*)(afl + ((((i << 1) + 0) << 6) + l) * 8);
      const b8 al1 = *(const b8*)(afl + ((((i << 1) + 1) << 6) + l) * 8);
      const b8 bh = *(const b8*)&Xh[ky][col + kx][qc];
      const b8 bl = *(const b8*)&Xl[ky][col + kx][qc];
      acc[0] = __builtin_amdgcn_mfma_f32_16x16x32_bf16(ah0, bh, acc[0], 0, 0, 0);
      acc[0] = __builtin_amdgcn_mfma_f32_16x16x32_bf16(ah0, bl, acc[0], 0, 0, 0);
      acc[0] = __builtin_amdgcn_mfma_f32_16x16x32_bf16(al0, bh, acc[0], 0, 0, 0);
      acc[1] = __builtin_amdgcn_mfma_f32_16x16x32_bf16(ah1, bh, acc[1], 0, 0, 0);
      acc[1] = __builtin_amdgcn_mfma_f32_16x16x32_bf16(ah1, bl, acc[1], 0, 0, 0);
      acc[1] = __builtin_amdgcn_mfma_f32_16x16x32_bf16(al1, bh, acc[1], 0, 0, 0);
    }
  }

  const int wo = col;
  const int q4 = (l >> 4) << 2;
#pragma unroll
  for (int mt = 0; mt < 2; ++mt)
#pragma unroll
    for (int r = 0; r < 4; ++r) {
      const int oc = (mt << 4) + q4 + r;
      if (oc < 18)
        atomicAdd(&ws[OF2 + ((b * 18 + oc) << 12) + (ho << 6) + wo],
                  acc[mt][r]);
    }
}

// ---------------------------------------------------------------------------
// K2 (R10 verbatim): half2-dup weights + 4 corner positions.
// ---------------------------------------------------------------------------
__global__ __launch_bounds__(256) void make_desc_xt(
    const float* __restrict__ bof, float* __restrict__ ws) {
  const int d  = blockIdx.x * 256 + threadIdx.x;
  const int k  = d >> 14;
  const int n  = d & 16383;
  const int b  = n >> 12;
  const int sp = n & 4095;
  const int ho = sp >> 6, wo = sp & 63;
  const int ky = k / 3, kx = k - ky * 3;
  const float dy = ws[OF2 + ((b * 18 + (k << 1)) << 12) + sp] + bof[k << 1];
  const float dx = ws[OF2 + ((b * 18 + (k << 1) + 1) << 12) + sp] + bof[(k << 1) + 1];
  const float py = (float)(ho - 1 + ky) + dy;
  const float px = (float)(wo - 1 + kx) + dx;
  const float y0f = floorf(py), x0f = floorf(px);
  const float ly = py - y0f, lx = px - x0f;
  const int y0 = (int)y0f, x0 = (int)x0f;
  const int y1 = y0 + 1, x1 = x0 + 1;
  const float vy0 = (y0 >= 0 && y0 < 64) ? 1.f : 0.f;
  const float vy1 = (y1 >= 0 && y1 < 64) ? 1.f : 0.f;
  const float vx0 = (x0 >= 0 && x0 < 64) ? 1.f : 0.f;
  const float vx1 = (x1 >= 0 && x1 < 64) ? 1.f : 0.f;
  const int y0c = min(max(y0, 0), 63), y1c = min(max(y1, 0), 63);
  const int x0c = min(max(x0, 0), 63), x1c = min(max(x1, 0), 63);
  uint4 wv;
  wv.x = duph((1.f - ly) * (1.f - lx) * vy0 * vx0);
  wv.y = duph((1.f - ly) * lx * vy0 * vx1);
  wv.z = duph(ly * (1.f - lx) * vy1 * vx0);
  wv.w = duph(ly * lx * vy1 * vx1);
  int4 pv;
  pv.x = (y0c << 6) + x0c;
  pv.y = (y0c << 6) + x1c;
  pv.z = (y1c << 6) + x0c;
  pv.w = (y1c << 6) + x1c;
  ((uint4*)(ws + DW2))[d] = wv;
  ((int4*)(ws + DP2))[d] = pv;
}

// ---------------------------------------------------------------------------
// K3: R10's f16 MFMA GEMM structure (triple-buffered, LDS-shared B) at
// 2+ blocks/CU: grid 512 x 256 thr (4 waves), block tile 256o x 32n,
// wave = 64o x 32n. B gathered once device-wide; cross-BLOCK overlap fills
// each block's per-iter barrier drain (independent barriers).
// ---------------------------------------------------------------------------
__global__ __launch_bounds__(256, 2) void deform_gemm_f16b(
    const float* __restrict__ ws, float* __restrict__ out) {
  __shared__ __align__(16) uint Bs[3][32][32];   // 12 KB f16 tiles
  __shared__ uint4 dW[288];                      // 4.5 KB
  __shared__ int4  dP[288];                      // 4.5 KB

  const int t     = threadIdx.x;
  const int bid   = blockIdx.x;
  const int xcd   = bid & 7;
  const int batch = xcd >> 1;
  const int half  = xcd & 1;
  const int j     = bid >> 3;                    // 0..63
  const int sp0   = (half << 11) + (j << 5);
  const int nd0   = (batch << 12) + sp0;
  const int l     = t & 63;
  const int wv    = t >> 6;                      // 0..3

  // staging ids: wave covers 16 samples x 4 contiguous 16B slices (line-local)
  const int sn  = ((wv & 1) << 4) | (l & 15);    // sample column 0..31
  const int cg8 = ((wv >> 1) << 2) | (l >> 4);   // 8-ch slice 0..7
  const uint* xtu = (const uint*)(ws + XT2) + ((long)batch << 19);
  const _Float16* af = (const _Float16*)(ws + AF2);

  // fill descriptor LDS: 288 = 9 kk x 32 samples
  for (int u = t; u < 288; u += 256) {
    const int kk = u >> 5, s = u & 31;
    const int dg = (kk << 14) + nd0 + s;
    dW[u] = ((const uint4*)(ws + DW2))[dg];
    dP[u] = ((const int4*)(ws + DP2))[dg];
  }
  __syncthreads();

  f4 acc[4][2];
#pragma unroll
  for (int m = 0; m < 4; ++m)
#pragma unroll
    for (int nt = 0; nt < 2; ++nt) acc[m][nt] = f4{0.f, 0.f, 0.f, 0.f};

  uint4 cset0[4], cset1[4];           // two outstanding corner sets
  uint4 w0v, w1v, wq; int4 pq;
  h8 aA[4][2], aN[4][2];
  int kkd, kkg, cwg, bufc;

#define FRDD(W_, P_, KK_) do { const int u_ = ((KK_) << 5) + sn;             \
    W_ = dW[u_]; P_ = dP[u_]; } while (0)

#define FGATH(DST_, P_) do {                                                 \
    const int co_ = (cwg << 5) + (cg8 << 2);                                 \
    DST_[0] = *(const uint4*)(xtu + ((P_).x << 7) + co_);                    \
    DST_[1] = *(const uint4*)(xtu + ((P_).y << 7) + co_);                    \
    DST_[2] = *(const uint4*)(xtu + ((P_).z << 7) + co_);                    \
    DST_[3] = *(const uint4*)(xtu + ((P_).w << 7) + co_);                    \
  } while (0)

#define FCOMB(CS_, WV_, BUF_) do {                                           \
    const h2 wc0_ = u2h2((WV_).x), wc1_ = u2h2((WV_).y);                     \
    const h2 wc2_ = u2h2((WV_).z), wc3_ = u2h2((WV_).w);                     \
    uint4 r_;                                                                \
    r_.x = h22u(u2h2(CS_[0].x) * wc0_ + u2h2(CS_[1].x) * wc1_ +              \
                u2h2(CS_[2].x) * wc2_ + u2h2(CS_[3].x) * wc3_);              \
    r_.y = h22u(u2h2(CS_[0].y) * wc0_ + u2h2(CS_[1].y) * wc1_ +              \
                u2h2(CS_[2].y) * wc2_ + u2h2(CS_[3].y) * wc3_);              \
    r_.z = h22u(u2h2(CS_[0].z) * wc0_ + u2h2(CS_[1].z) * wc1_ +              \
                u2h2(CS_[2].z) * wc2_ + u2h2(CS_[3].z) * wc3_);              \
    r_.w = h22u(u2h2(CS_[0].w) * wc0_ + u2h2(CS_[1].w) * wc1_ +              \
                u2h2(CS_[2].w) * wc2_ + u2h2(CS_[3].w) * wc3_);              \
    *(uint4*)&Bs[BUF_][sn][(cg8 ^ (sn & 7)) << 2] = r_;                      \
  } while (0)

#define FLOADA(I_, DST_) do {                                                \
    _Pragma("unroll")                                                        \
    for (int m = 0; m < 4; ++m)                                              \
      _Pragma("unroll")                                                      \
      for (int s = 0; s < 2; ++s) {                                          \
        const int f_ = ((I_) << 1) + s;                                      \
        DST_[m][s] = *(const h8*)(af +                                       \
            ((((f_ << 4) + (wv << 2) + m) << 6) + l) * 8);                   \
      }                                                                      \
  } while (0)

#define FMFMA(AC_, BUF_) do {                                                \
    h8 bB_[2][2];                                                            \
    _Pragma("unroll")                                                        \
    for (int nt = 0; nt < 2; ++nt)                                           \
      _Pragma("unroll")                                                      \
      for (int s = 0; s < 2; ++s) {                                          \
        const int snr_ = (nt << 4) + (l & 15);                               \
        const int ph_  = (((s << 2) + (l >> 4)) ^ (snr_ & 7)) << 2;          \
        bB_[nt][s] = *(const h8*)&Bs[BUF_][snr_][ph_];                       \
      }                                                                      \
    _Pragma("unroll")                                                        \
    for (int m = 0; m < 4; ++m)                                              \
      _Pragma("unroll")                                                      \
      for (int nt = 0; nt < 2; ++nt) {                                       \
        acc[m][nt] = __builtin_amdgcn_mfma_f32_16x16x32_f16(                 \
            AC_[m][0], bB_[nt][0], acc[m][nt], 0, 0, 0);                     \
        acc[m][nt] = __builtin_amdgcn_mfma_f32_16x16x32_f16(                 \
            AC_[m][1], bB_[nt][1], acc[m][nt], 0, 0, 0);                     \
      }                                                                      \
  } while (0)

#define FBODY(I_, AC_, AN_, CC_, WC_, CN_, WN_) do {                         \
    if ((I_) < 34) {                                                         \
      WN_ = wq; FGATH(CN_, pq);                                              \
      kkg++; if (kkg == 9) { kkg = 0; cwg++; }                               \
    }                                                                        \
    if ((I_) < 33) { FRDD(wq, pq, kkd); kkd = (kkd == 8) ? 0 : kkd + 1; }    \
    const int bufn_ = (bufc == 2) ? 0 : bufc + 1;                            \
    FMFMA(AC_, bufc);                                                        \
    if ((I_) < 35) {                                                         \
      FLOADA((I_) + 1, AN_);                                                 \
      FCOMB(CC_, WC_, bufn_);                                                \
    }                                                                        \
    bufc = bufn_;                                                            \
    __syncthreads();                                                         \
  } while (0)

  // ---- prologue: gather iters 0 and 1 (cw=0), desc queue = iter 2 ----
  {
    uint4 wA; int4 pA;
    cwg = 0;
    FRDD(wA, pA, 0);
    FGATH(cset0, pA);
    FRDD(w1v, pA, 1);
    FGATH(cset1, pA);
    FRDD(wq, pq, 2);
    FLOADA(0, aA);
    FCOMB(cset0, wA, 0);
    kkd = 3; kkg = 2; bufc = 0;
  }
  __syncthreads();

  for (int i = 0; i < 36; i += 2) {
    FBODY(i,     aA, aN, cset1, w1v, cset0, w0v);
    FBODY(i + 1, aN, aA, cset0, w0v, cset1, w1v);
  }

  const float* bfold = ws + BF2;
  const int quad = l >> 4;
  const int ow = wv << 6;
#pragma unroll
  for (int m = 0; m < 4; ++m) {
    const int ob = ow + (m << 4) + (quad << 2);
    const f4 bf = *(const f4*)&bfold[ob];
#pragma unroll
    for (int nt = 0; nt < 2; ++nt) {
      const int sp = sp0 + (nt << 4) + (l & 15);
#pragma unroll
      for (int r = 0; r < 4; ++r) {
        out[(((batch << 8) + ob + r) << 12) + sp] =
            fmaxf(acc[m][nt][r] + bf[r], 0.f);
      }
    }
  }
}

// ---------------------------------------------------------------------------
extern "C" void kernel_launch(void* const* d_in, const int* in_sizes, int n_in,
                              void* d_out, int out_size, void* d_ws, size_t ws_size,
                              hipStream_t stream) {
  const float* x     = (const float*)d_in[0];
  const float* wof   = (const float*)d_in[1];
  const float* bof   = (const float*)d_in[2];
  const float* w     = (const float*)d_in[3];
  const float* bias  = (const float*)d_in[4];
  const float* gamma = (const float*)d_in[5];
  const float* beta  = (const float*)d_in[6];
  const float* mean  = (const float*)d_in[7];
  const float* var   = (const float*)d_in[8];
  float* out = (float*)d_out;
  float* ws  = (float*)d_ws;

  hipLaunchKernelGGL(prep_k, dim3(288), dim3(256), 0, stream,
                     w, wof, bias, gamma, beta, mean, var, ws);
  hipLaunchKernelGGL(transpose_k, dim3(2048), dim3(256), 0, stream, x, ws);
  hipLaunchKernelGGL(offset_part_k, dim3(1024), dim3(256), 0, stream, x, ws);
  hipLaunchKernelGGL(make_desc_xt, dim3(576), dim3(256), 0, stream, bof, ws);
  hipLaunchKernelGGL(deform_gemm_f16b, dim3(512), dim3(256), 0, stream,
                     ws, out);
}

// Round 13
// 156.511 us; speedup vs baseline: 1.5968x; 1.0332x over previous
//
#include <hip/hip_runtime.h>
#include <math.h>

typedef __attribute__((ext_vector_type(8))) short b8;
typedef __attribute__((ext_vector_type(4))) float f4;
typedef float f4u __attribute__((ext_vector_type(4), aligned(4)));
typedef _Float16 h8 __attribute__((ext_vector_type(8)));
typedef _Float16 h2 __attribute__((ext_vector_type(2)));

// ---------------- ws layout (float offsets) --------------------------------
#define XT2   0                     // f16[4*4096*256] = 2097152 floats
#define OF2   2097152               // 294912 (fp32 accumulated offsets)
#define WH2   2392064               // bf16-split offset-conv weights (hi)
#define WL2   2428928               // (lo)
#define AF2   3571712               // f16[589824] main A-frags
#define BF2   3866624               // 256 folded bias

__device__ inline ushort f2bf(float f) {
  uint u = __float_as_uint(f);
  return (ushort)((u + 0x7FFFu + ((u >> 16) & 1u)) >> 16);
}
__device__ inline h2 u2h2(uint u) { union { uint u; h2 h; } x; x.u = u; return x.h; }
__device__ inline uint h22u(h2 h) { union { uint u; h2 h; } x; x.h = h; return x.u; }
__device__ inline uint duph(float f) {
  union { _Float16 h; ushort u; } x; x.h = (_Float16)f;
  return ((uint)x.u << 16) | x.u;
}

// ---------------------------------------------------------------------------
// K0: fused prep + transpose. Grid 2336: bid<2048 -> transpose slice,
// bid>=2048 -> prep slice (288 blocks).
// ---------------------------------------------------------------------------
__global__ __launch_bounds__(256) void pre_k(
    const float* __restrict__ x, const float* __restrict__ w,
    const float* __restrict__ wof, const float* __restrict__ bias,
    const float* __restrict__ gamma, const float* __restrict__ beta,
    const float* __restrict__ mean, const float* __restrict__ var,
    float* __restrict__ ws) {
  const int bid = blockIdx.x;
  if (bid < 2048) {
    // ---- transpose: x (B,C,H,W) fp32 -> xt (B,P,C) f16 ----
    const int id  = bid * 256 + threadIdx.x;
    const int p   = id & 4095;
    const int cg8 = (id >> 12) & 31;
    const int b   = id >> 17;
    const float* xp = x + (((long)(b * 256 + cg8 * 8)) << 12) + p;
    _Float16* xt = (_Float16*)(ws + XT2);
    h8 pk;
#pragma unroll
    for (int j = 0; j < 8; ++j) pk[j] = (_Float16)xp[(long)j << 12];
    *(h8*)(xt + ((((long)(b << 12) + p)) << 8) + (cg8 << 3)) = pk;
    return;
  }
  // ---- prep ----
  const int tid = (bid - 2048) * 256 + threadIdx.x;   // < 73728
  const int l  = tid & 63;
  const int ot = (tid >> 6) & 15;
  const int f  = tid >> 10;
  const int o  = (ot << 4) + (l & 15);
  const float inv = gamma[o] * rsqrtf(var[o] + 1e-5f);
  {
    const int s  = f & 1;
    const int g  = f >> 1;
    const int cw = g / 9;
    const int kk = g - cw * 9;
    const int cb = (cw << 6) + (s << 5) + ((l >> 4) << 3);
    h8 pk;
#pragma unroll
    for (int j = 0; j < 8; ++j)
      pk[j] = (_Float16)(w[((o << 8) + cb + j) * 9 + kk] * inv);
    *(h8*)((_Float16*)(ws + AF2) + tid * 8) = pk;
    ((f4*)(ws + OF2))[tid] = f4{0.f, 0.f, 0.f, 0.f};
  }
  if (tid < 256) {
    const float iv = gamma[tid] * rsqrtf(var[tid] + 1e-5f);
    ws[BF2 + tid] = bias[tid] * iv + beta[tid] - mean[tid] * iv;
  }
  if (tid < 9216) {
    const int l2  = tid & 63;
    const int mt  = (tid >> 6) & 1;
    const int i2  = tid >> 7;
    const int cg2 = i2 / 9;
    const int kk2 = i2 - cg2 * 9;
    const int oc  = (mt << 4) + (l2 & 15);
    const int cb2 = (cg2 << 5) + ((l2 >> 4) << 3);
    b8 ph, pl;
#pragma unroll
    for (int j = 0; j < 8; ++j) {
      const float v = (oc < 18) ? wof[((oc << 8) + cb2 + j) * 9 + kk2] : 0.f;
      const ushort h = f2bf(v);
      const float hf = __uint_as_float((uint)h << 16);
      ph[j] = (short)h;
      pl[j] = (short)f2bf(v - hf);
    }
    *(b8*)((short*)(ws + WH2) + tid * 8) = ph;
    *(b8*)((short*)(ws + WL2) + tid * 8) = pl;
  }
}

// ---------------------------------------------------------------------------
// K1 (R12 verbatim): offset conv K-split x4, atomics into OF2.
// ---------------------------------------------------------------------------
__global__ __launch_bounds__(256, 4) void offset_part_k(
    const float* __restrict__ x, float* __restrict__ ws) {
  __shared__ __align__(16) ushort Xh[3][66][40];
  __shared__ __align__(16) ushort Xl[3][66][40];
  const int bid = blockIdx.x;
  const int q   = bid >> 8;
  const int b   = (bid >> 6) & 3;
  const int ho  = bid & 63;
  const int t   = threadIdx.x;
  const int l   = t & 63;
  const int wv  = t >> 6;
  const short* afh = (const short*)(ws + WH2);
  const short* afl = (const short*)(ws + WL2);

  for (int u = t; u < 240; u += 256) {
    const int row = u / 80, rem = u % 80;
    const int col = (rem >= 40) ? 65 : 0;
    const int c   = rem % 40;
    Xh[row][col][c] = 0;
    Xl[row][col][c] = 0;
  }

  f4 acc[2];
  acc[0] = f4{0.f, 0.f, 0.f, 0.f};
  acc[1] = f4{0.f, 0.f, 0.f, 0.f};

  const int cidx = t >> 3;
  const int j8   = t & 7;
  const float* xc = x + ((long)b << 20) + ((long)cidx << 12);
  const int col = (wv << 4) + (l & 15);
  const int qc  = (l >> 4) << 3;

  for (int it = 0; it < 2; ++it) {
    const int cg = (q << 1) + it;
    __syncthreads();
    const float* xg = xc + ((long)(cg << 5) << 12);
#pragma unroll
    for (int rep = 0; rep < 6; ++rep) {
      const int fi   = (rep << 3) + j8;
      const int row  = fi >> 4;
      const int colf = (fi & 15) << 2;
      const int y = ho - 1 + row;
      f4u v = {0.f, 0.f, 0.f, 0.f};
      if (y >= 0 && y <= 63) v = *(const f4u*)(xg + (y << 6) + colf);
#pragma unroll
      for (int qq = 0; qq < 4; ++qq) {
        const ushort h = f2bf(v[qq]);
        const float hf = __uint_as_float((uint)h << 16);
        Xh[row][colf + 1 + qq][cidx] = h;
        Xl[row][colf + 1 + qq][cidx] = f2bf(v[qq] - hf);
      }
    }
    __syncthreads();
#pragma unroll
    for (int kk = 0; kk < 9; ++kk) {
      const int ky = kk / 3, kx = kk - ky * 3;
      const int i  = cg * 9 + kk;
      const b8 ah0 = *(const b8*)(afh + ((((i << 1) + 0) << 6) + l) * 8);
      const b8 ah1 = *(const b8*)(afh + ((((i << 1) + 1) << 6) + l) * 8);
      const b8 al0 = *(const b8*)(afl + ((((i << 1) + 0) << 6) + l) * 8);
      const b8 al1 = *(const b8*)(afl + ((((i << 1) + 1) << 6) + l) * 8);
      const b8 bh = *(const b8*)&Xh[ky][col + kx][qc];
      const b8 bl = *(const b8*)&Xl[ky][col + kx][qc];
      acc[0] = __builtin_amdgcn_mfma_f32_16x16x32_bf16(ah0, bh, acc[0], 0, 0, 0);
      acc[0] = __builtin_amdgcn_mfma_f32_16x16x32_bf16(ah0, bl, acc[0], 0, 0, 0);
      acc[0] = __builtin_amdgcn_mfma_f32_16x16x32_bf16(al0, bh, acc[0], 0, 0, 0);
      acc[1] = __builtin_amdgcn_mfma_f32_16x16x32_bf16(ah1, bh, acc[1], 0, 0, 0);
      acc[1] = __builtin_amdgcn_mfma_f32_16x16x32_bf16(ah1, bl, acc[1], 0, 0, 0);
      acc[1] = __builtin_amdgcn_mfma_f32_16x16x32_bf16(al1, bh, acc[1], 0, 0, 0);
    }
  }

  const int wo = col;
  const int q4 = (l >> 4) << 2;
#pragma unroll
  for (int mt = 0; mt < 2; ++mt)
#pragma unroll
    for (int r = 0; r < 4; ++r) {
      const int oc = (mt << 4) + q4 + r;
      if (oc < 18)
        atomicAdd(&ws[OF2 + ((b * 18 + oc) << 12) + (ho << 6) + wo],
                  acc[mt][r]);
    }
}

// ---------------------------------------------------------------------------
// K2: f16 MFMA GEMM (R12 structure) with FUSED descriptor computation.
// Grid 512 x 256 thr (4 waves), block tile 256o x 32n. Each block computes
// its own 288 descriptors (9kk x 32n) from OF2+bof into LDS — zero
// duplication device-wide, no separate make_desc kernel, no DW2/DP2 traffic.
// ---------------------------------------------------------------------------
__global__ __launch_bounds__(256, 2) void deform_gemm_f16b(
    const float* __restrict__ ws, const float* __restrict__ bof,
    float* __restrict__ out) {
  __shared__ __align__(16) uint Bs[3][32][32];   // 12 KB f16 tiles
  __shared__ uint4 dW[288];                      // 4.5 KB
  __shared__ int4  dP[288];                      // 4.5 KB

  const int t     = threadIdx.x;
  const int bid   = blockIdx.x;
  const int xcd   = bid & 7;
  const int batch = xcd >> 1;
  const int half  = xcd & 1;
  const int j     = bid >> 3;                    // 0..63
  const int sp0   = (half << 11) + (j << 5);
  const int l     = t & 63;
  const int wv    = t >> 6;                      // 0..3

  // staging ids: wave covers 16 samples x 4 contiguous 16B slices (line-local)
  const int sn  = ((wv & 1) << 4) | (l & 15);    // sample column 0..31
  const int cg8 = ((wv >> 1) << 2) | (l >> 4);   // 8-ch slice 0..7
  const uint* xtu = (const uint*)(ws + XT2) + ((long)batch << 19);
  const _Float16* af = (const _Float16*)(ws + AF2);

  // ---- fused descriptor computation: 288 = 9 kk x 32 samples ----
  for (int u = t; u < 288; u += 256) {
    const int kk = u >> 5, s = u & 31;
    const int sp = sp0 + s;
    const int ho = sp >> 6, wo = sp & 63;
    const int ky = kk / 3, kx = kk - ky * 3;
    const float dy =
        ws[OF2 + ((batch * 18 + (kk << 1)) << 12) + sp] + bof[kk << 1];
    const float dx =
        ws[OF2 + ((batch * 18 + (kk << 1) + 1) << 12) + sp] + bof[(kk << 1) + 1];
    const float py = (float)(ho - 1 + ky) + dy;
    const float px = (float)(wo - 1 + kx) + dx;
    const float y0f = floorf(py), x0f = floorf(px);
    const float ly = py - y0f, lx = px - x0f;
    const int y0 = (int)y0f, x0 = (int)x0f;
    const int y1 = y0 + 1, x1 = x0 + 1;
    const float vy0 = (y0 >= 0 && y0 < 64) ? 1.f : 0.f;
    const float vy1 = (y1 >= 0 && y1 < 64) ? 1.f : 0.f;
    const float vx0 = (x0 >= 0 && x0 < 64) ? 1.f : 0.f;
    const float vx1 = (x1 >= 0 && x1 < 64) ? 1.f : 0.f;
    const int y0c = min(max(y0, 0), 63), y1c = min(max(y1, 0), 63);
    const int x0c = min(max(x0, 0), 63), x1c = min(max(x1, 0), 63);
    uint4 wv4;
    wv4.x = duph((1.f - ly) * (1.f - lx) * vy0 * vx0);
    wv4.y = duph((1.f - ly) * lx * vy0 * vx1);
    wv4.z = duph(ly * (1.f - lx) * vy1 * vx0);
    wv4.w = duph(ly * lx * vy1 * vx1);
    int4 pv;
    pv.x = (y0c << 6) + x0c;
    pv.y = (y0c << 6) + x1c;
    pv.z = (y1c << 6) + x0c;
    pv.w = (y1c << 6) + x1c;
    dW[u] = wv4;
    dP[u] = pv;
  }
  __syncthreads();

  f4 acc[4][2];
#pragma unroll
  for (int m = 0; m < 4; ++m)
#pragma unroll
    for (int nt = 0; nt < 2; ++nt) acc[m][nt] = f4{0.f, 0.f, 0.f, 0.f};

  uint4 cset0[4], cset1[4];           // two outstanding corner sets
  uint4 w0v, w1v, wq; int4 pq;
  h8 aA[4][2], aN[4][2];
  int kkd, kkg, cwg, bufc;

#define FRDD(W_, P_, KK_) do { const int u_ = ((KK_) << 5) + sn;             \
    W_ = dW[u_]; P_ = dP[u_]; } while (0)

#define FGATH(DST_, P_) do {                                                 \
    const int co_ = (cwg << 5) + (cg8 << 2);                                 \
    DST_[0] = *(const uint4*)(xtu + ((P_).x << 7) + co_);                    \
    DST_[1] = *(const uint4*)(xtu + ((P_).y << 7) + co_);                    \
    DST_[2] = *(const uint4*)(xtu + ((P_).z << 7) + co_);                    \
    DST_[3] = *(const uint4*)(xtu + ((P_).w << 7) + co_);                    \
  } while (0)

#define FCOMB(CS_, WV_, BUF_) do {                                           \
    const h2 wc0_ = u2h2((WV_).x), wc1_ = u2h2((WV_).y);                     \
    const h2 wc2_ = u2h2((WV_).z), wc3_ = u2h2((WV_).w);                     \
    uint4 r_;                                                                \
    r_.x = h22u(u2h2(CS_[0].x) * wc0_ + u2h2(CS_[1].x) * wc1_ +              \
                u2h2(CS_[2].x) * wc2_ + u2h2(CS_[3].x) * wc3_);              \
    r_.y = h22u(u2h2(CS_[0].y) * wc0_ + u2h2(CS_[1].y) * wc1_ +              \
                u2h2(CS_[2].y) * wc2_ + u2h2(CS_[3].y) * wc3_);              \
    r_.z = h22u(u2h2(CS_[0].z) * wc0_ + u2h2(CS_[1].z) * wc1_ +              \
                u2h2(CS_[2].z) * wc2_ + u2h2(CS_[3].z) * wc3_);              \
    r_.w = h22u(u2h2(CS_[0].w) * wc0_ + u2h2(CS_[1].w) * wc1_ +              \
                u2h2(CS_[2].w) * wc2_ + u2h2(CS_[3].w) * wc3_);              \
    *(uint4*)&Bs[BUF_][sn][(cg8 ^ (sn & 7)) << 2] = r_;                      \
  } while (0)

#define FLOADA(I_, DST_) do {                                                \
    _Pragma("unroll")                                                        \
    for (int m = 0; m < 4; ++m)                                              \
      _Pragma("unroll")                                                      \
      for (int s = 0; s < 2; ++s) {                                          \
        const int f_ = ((I_) << 1) + s;                                      \
        DST_[m][s] = *(const h8*)(af +                                       \
            ((((f_ << 4) + (wv << 2) + m) << 6) + l) * 8);                   \
      }                                                                      \
  } while (0)

#define FMFMA(AC_, BUF_) do {                                                \
    h8 bB_[2][2];                                                            \
    _Pragma("unroll")                                                        \
    for (int nt = 0; nt < 2; ++nt)                                           \
      _Pragma("unroll")                                                      \
      for (int s = 0; s < 2; ++s) {                                          \
        const int snr_ = (nt << 4) + (l & 15);                               \
        const int ph_  = (((s << 2) + (l >> 4)) ^ (snr_ & 7)) << 2;          \
        bB_[nt][s] = *(const h8*)&Bs[BUF_][snr_][ph_];                       \
      }                                                                      \
    _Pragma("unroll")                                                        \
    for (int m = 0; m < 4; ++m)                                              \
      _Pragma("unroll")                                                      \
      for (int nt = 0; nt < 2; ++nt) {                                       \
        acc[m][nt] = __builtin_amdgcn_mfma_f32_16x16x32_f16(                 \
            AC_[m][0], bB_[nt][0], acc[m][nt], 0, 0, 0);                     \
        acc[m][nt] = __builtin_amdgcn_mfma_f32_16x16x32_f16(                 \
            AC_[m][1], bB_[nt][1], acc[m][nt], 0, 0, 0);                     \
      }                                                                      \
  } while (0)

#define FBODY(I_, AC_, AN_, CC_, WC_, CN_, WN_) do {                         \
    if ((I_) < 34) {                                                         \
      WN_ = wq; FGATH(CN_, pq);                                              \
      kkg++; if (kkg == 9) { kkg = 0; cwg++; }                               \
    }                                                                        \
    if ((I_) < 33) { FRDD(wq, pq, kkd); kkd = (kkd == 8) ? 0 : kkd + 1; }    \
    const int bufn_ = (bufc == 2) ? 0 : bufc + 1;                            \
    FMFMA(AC_, bufc);                                                        \
    if ((I_) < 35) {                                                         \
      FLOADA((I_) + 1, AN_);                                                 \
      FCOMB(CC_, WC_, bufn_);                                                \
    }                                                                        \
    bufc = bufn_;                                                            \
    __syncthreads();                                                         \
  } while (0)

  // ---- prologue: gather iters 0 and 1 (cw=0), desc queue = iter 2 ----
  {
    uint4 wA; int4 pA;
    cwg = 0;
    FRDD(wA, pA, 0);
    FGATH(cset0, pA);
    FRDD(w1v, pA, 1);
    FGATH(cset1, pA);
    FRDD(wq, pq, 2);
    FLOADA(0, aA);
    FCOMB(cset0, wA, 0);
    kkd = 3; kkg = 2; bufc = 0;
  }
  __syncthreads();

  for (int i = 0; i < 36; i += 2) {
    FBODY(i,     aA, aN, cset1, w1v, cset0, w0v);
    FBODY(i + 1, aN, aA, cset0, w0v, cset1, w1v);
  }

  const float* bfold = ws + BF2;
  const int quad = l >> 4;
  const int ow = wv << 6;
#pragma unroll
  for (int m = 0; m < 4; ++m) {
    const int ob = ow + (m << 4) + (quad << 2);
    const f4 bf = *(const f4*)&bfold[ob];
#pragma unroll
    for (int nt = 0; nt < 2; ++nt) {
      const int sp = sp0 + (nt << 4) + (l & 15);
#pragma unroll
      for (int r = 0; r < 4; ++r) {
        out[(((batch << 8) + ob + r) << 12) + sp] =
            fmaxf(acc[m][nt][r] + bf[r], 0.f);
      }
    }
  }
}

// ---------------------------------------------------------------------------
extern "C" void kernel_launch(void* const* d_in, const int* in_sizes, int n_in,
                              void* d_out, int out_size, void* d_ws, size_t ws_size,
                              hipStream_t stream) {
  const float* x     = (const float*)d_in[0];
  const float* wof   = (const float*)d_in[1];
  const float* bof   = (const float*)d_in[2];
  const float* w     = (const float*)d_in[3];
  const float* bias  = (const float*)d_in[4];
  const float* gamma = (const float*)d_in[5];
  const float* beta  = (const float*)d_in[6];
  const float* mean  = (const float*)d_in[7];
  const float* var   = (const float*)d_in[8];
  float* out = (float*)d_out;
  float* ws  = (float*)d_ws;

  hipLaunchKernelGGL(pre_k, dim3(2336), dim3(256), 0, stream,
                     x, w, wof, bias, gamma, beta, mean, var, ws);
  hipLaunchKernelGGL(offset_part_k, dim3(1024), dim3(256), 0, stream, x, ws);
  hipLaunchKernelGGL(deform_gemm_f16b, dim3(512), dim3(256), 0, stream,
                     ws, bof, out);
}

// Round 14
// 154.183 us; speedup vs baseline: 1.6209x; 1.0151x over previous
//
#include <hip/hip_runtime.h>
#include <math.h>

typedef __attribute__((ext_vector_type(8))) short b8;
typedef __attribute__((ext_vector_type(4))) float f4;
typedef float f4u __attribute__((ext_vector_type(4), aligned(4)));
typedef _Float16 h8 __attribute__((ext_vector_type(8)));
typedef _Float16 h2 __attribute__((ext_vector_type(2)));

// ---------------- ws layout (float offsets) --------------------------------
#define XT2   0                     // f16[4*4096*256] = 2097152 floats
#define OF2   2097152               // 294912 (fp32 accumulated offsets)
#define WH2   2392064               // bf16-split offset-conv weights (hi)
#define WL2   2428928               // (lo)
#define AF2   3571712               // f16[589824] main A-frags
#define BF2   3866624               // 256 folded bias

__device__ inline ushort f2bf(float f) {
  uint u = __float_as_uint(f);
  return (ushort)((u + 0x7FFFu + ((u >> 16) & 1u)) >> 16);
}
__device__ inline h2 u2h2(uint u) { union { uint u; h2 h; } x; x.u = u; return x.h; }
__device__ inline uint h22u(h2 h) { union { uint u; h2 h; } x; x.h = h; return x.u; }
__device__ inline uint duph(float f) {
  union { _Float16 h; ushort u; } x; x.h = (_Float16)f;
  return ((uint)x.u << 16) | x.u;
}

// ---------------------------------------------------------------------------
// K0: minimal prep needed by K1's offset blocks: zero OF2, folded bias,
// bf16-split offset-conv weight frags. 288 blocks.
// ---------------------------------------------------------------------------
__global__ __launch_bounds__(256) void prep0_k(
    const float* __restrict__ wof, const float* __restrict__ bias,
    const float* __restrict__ gamma, const float* __restrict__ beta,
    const float* __restrict__ mean, const float* __restrict__ var,
    float* __restrict__ ws) {
  const int tid = blockIdx.x * 256 + threadIdx.x;   // < 73728
  ((f4*)(ws + OF2))[tid] = f4{0.f, 0.f, 0.f, 0.f};
  if (tid < 256) {
    const float iv = gamma[tid] * rsqrtf(var[tid] + 1e-5f);
    ws[BF2 + tid] = bias[tid] * iv + beta[tid] - mean[tid] * iv;
  }
  if (tid < 9216) {
    const int l2  = tid & 63;
    const int mt  = (tid >> 6) & 1;
    const int i2  = tid >> 7;
    const int cg2 = i2 / 9;
    const int kk2 = i2 - cg2 * 9;
    const int oc  = (mt << 4) + (l2 & 15);
    const int cb2 = (cg2 << 5) + ((l2 >> 4) << 3);
    b8 ph, pl;
#pragma unroll
    for (int j = 0; j < 8; ++j) {
      const float v = (oc < 18) ? wof[((oc << 8) + cb2 + j) * 9 + kk2] : 0.f;
      const ushort h = f2bf(v);
      const float hf = __uint_as_float((uint)h << 16);
      ph[j] = (short)h;
      pl[j] = (short)f2bf(v - hf);
    }
    *(b8*)((short*)(ws + WH2) + tid * 8) = ph;
    *(b8*)((short*)(ws + WL2) + tid * 8) = pl;
  }
}

// ---------------------------------------------------------------------------
// K1: fused transpose + offset-conv + main-A-frag pack. Grid 3360:
//   bid<3072: r=bid%3, g=bid/3; r==2 -> offset block g (1024),
//             else -> transpose block 2g+r (2048).
//   bid>=3072: A-frag pack block bid-3072 (288).
// Transpose (memory) and offset (MFMA chain) blocks co-schedule per CU.
// ---------------------------------------------------------------------------
__global__ __launch_bounds__(256, 4) void mid_k(
    const float* __restrict__ x, const float* __restrict__ w,
    const float* __restrict__ gamma, const float* __restrict__ var,
    float* __restrict__ ws) {
  __shared__ __align__(16) ushort Xh[3][66][40];
  __shared__ __align__(16) ushort Xl[3][66][40];
  const int bid = blockIdx.x;
  const int t   = threadIdx.x;

  if (bid >= 3072) {
    // ---- main-GEMM A-frag pack (prep mode-1 body) ----
    const int tid = (bid - 3072) * 256 + t;   // < 73728
    const int l  = tid & 63;
    const int ot = (tid >> 6) & 15;
    const int f  = tid >> 10;
    const int o  = (ot << 4) + (l & 15);
    const float inv = gamma[o] * rsqrtf(var[o] + 1e-5f);
    const int s  = f & 1;
    const int g  = f >> 1;
    const int cw = g / 9;
    const int kk = g - cw * 9;
    const int cb = (cw << 6) + (s << 5) + ((l >> 4) << 3);
    h8 pk;
#pragma unroll
    for (int j = 0; j < 8; ++j)
      pk[j] = (_Float16)(w[((o << 8) + cb + j) * 9 + kk] * inv);
    *(h8*)((_Float16*)(ws + AF2) + tid * 8) = pk;
    return;
  }

  const int r = bid % 3;
  const int g = bid / 3;
  if (r != 2) {
    // ---- transpose: x (B,C,H,W) fp32 -> xt (B,P,C) f16 ----
    const int id  = ((g << 1) + r) * 256 + t;   // < 524288
    const int p   = id & 4095;
    const int cg8 = (id >> 12) & 31;
    const int b   = id >> 17;
    const float* xp = x + (((long)(b * 256 + cg8 * 8)) << 12) + p;
    _Float16* xt = (_Float16*)(ws + XT2);
    h8 pk;
#pragma unroll
    for (int j = 0; j < 8; ++j) pk[j] = (_Float16)xp[(long)j << 12];
    *(h8*)(xt + ((((long)(b << 12) + p)) << 8) + (cg8 << 3)) = pk;
    return;
  }

  // ---- offset conv block g (R13 offset_part_k body) ----
  const int q   = g >> 8;
  const int b   = (g >> 6) & 3;
  const int ho  = g & 63;
  const int l   = t & 63;
  const int wv  = t >> 6;
  const short* afh = (const short*)(ws + WH2);
  const short* afl = (const short*)(ws + WL2);

  for (int u = t; u < 240; u += 256) {
    const int row = u / 80, rem = u % 80;
    const int col = (rem >= 40) ? 65 : 0;
    const int c   = rem % 40;
    Xh[row][col][c] = 0;
    Xl[row][col][c] = 0;
  }

  f4 acc[2];
  acc[0] = f4{0.f, 0.f, 0.f, 0.f};
  acc[1] = f4{0.f, 0.f, 0.f, 0.f};

  const int cidx = t >> 3;
  const int j8   = t & 7;
  const float* xc = x + ((long)b << 20) + ((long)cidx << 12);
  const int col = (wv << 4) + (l & 15);
  const int qc  = (l >> 4) << 3;

  for (int it = 0; it < 2; ++it) {
    const int cg = (q << 1) + it;
    __syncthreads();
    const float* xg = xc + ((long)(cg << 5) << 12);
#pragma unroll
    for (int rep = 0; rep < 6; ++rep) {
      const int fi   = (rep << 3) + j8;
      const int row  = fi >> 4;
      const int colf = (fi & 15) << 2;
      const int y = ho - 1 + row;
      f4u v = {0.f, 0.f, 0.f, 0.f};
      if (y >= 0 && y <= 63) v = *(const f4u*)(xg + (y << 6) + colf);
#pragma unroll
      for (int qq = 0; qq < 4; ++qq) {
        const ushort h = f2bf(v[qq]);
        const float hf = __uint_as_float((uint)h << 16);
        Xh[row][colf + 1 + qq][cidx] = h;
        Xl[row][colf + 1 + qq][cidx] = f2bf(v[qq] - hf);
      }
    }
    __syncthreads();
#pragma unroll
    for (int kk = 0; kk < 9; ++kk) {
      const int ky = kk / 3, kx = kk - ky * 3;
      const int i  = cg * 9 + kk;
      const b8 ah0 = *(const b8*)(afh + ((((i << 1) + 0) << 6) + l) * 8);
      const b8 ah1 = *(const b8*)(afh + ((((i << 1) + 1) << 6) + l) * 8);
      const b8 al0 = *(const b8*)(afl + ((((i << 1) + 0) << 6) + l) * 8);
      const b8 al1 = *(const b8*)(afl + ((((i << 1) + 1) << 6) + l) * 8);
      const b8 bh = *(const b8*)&Xh[ky][col + kx][qc];
      const b8 bl = *(const b8*)&Xl[ky][col + kx][qc];
      acc[0] = __builtin_amdgcn_mfma_f32_16x16x32_bf16(ah0, bh, acc[0], 0, 0, 0);
      acc[0] = __builtin_amdgcn_mfma_f32_16x16x32_bf16(ah0, bl, acc[0], 0, 0, 0);
      acc[0] = __builtin_amdgcn_mfma_f32_16x16x32_bf16(al0, bh, acc[0], 0, 0, 0);
      acc[1] = __builtin_amdgcn_mfma_f32_16x16x32_bf16(ah1, bh, acc[1], 0, 0, 0);
      acc[1] = __builtin_amdgcn_mfma_f32_16x16x32_bf16(ah1, bl, acc[1], 0, 0, 0);
      acc[1] = __builtin_amdgcn_mfma_f32_16x16x32_bf16(al1, bh, acc[1], 0, 0, 0);
    }
  }

  const int wo = col;
  const int q4 = (l >> 4) << 2;
#pragma unroll
  for (int mt = 0; mt < 2; ++mt)
#pragma unroll
    for (int rr = 0; rr < 4; ++rr) {
      const int oc = (mt << 4) + q4 + rr;
      if (oc < 18)
        atomicAdd(&ws[OF2 + ((b * 18 + oc) << 12) + (ho << 6) + wo],
                  acc[mt][rr]);
    }
}

// ---------------------------------------------------------------------------
// K2: f16 MFMA GEMM with fused descriptor computation (R13 verbatim).
// ---------------------------------------------------------------------------
__global__ __launch_bounds__(256, 2) void deform_gemm_f16b(
    const float* __restrict__ ws, const float* __restrict__ bof,
    float* __restrict__ out) {
  __shared__ __align__(16) uint Bs[3][32][32];   // 12 KB f16 tiles
  __shared__ uint4 dW[288];                      // 4.5 KB
  __shared__ int4  dP[288];                      // 4.5 KB

  const int t     = threadIdx.x;
  const int bid   = blockIdx.x;
  const int xcd   = bid & 7;
  const int batch = xcd >> 1;
  const int half  = xcd & 1;
  const int j     = bid >> 3;                    // 0..63
  const int sp0   = (half << 11) + (j << 5);
  const int l     = t & 63;
  const int wv    = t >> 6;                      // 0..3

  const int sn  = ((wv & 1) << 4) | (l & 15);    // sample column 0..31
  const int cg8 = ((wv >> 1) << 2) | (l >> 4);   // 8-ch slice 0..7
  const uint* xtu = (const uint*)(ws + XT2) + ((long)batch << 19);
  const _Float16* af = (const _Float16*)(ws + AF2);

  // ---- fused descriptor computation: 288 = 9 kk x 32 samples ----
  for (int u = t; u < 288; u += 256) {
    const int kk = u >> 5, s = u & 31;
    const int sp = sp0 + s;
    const int ho = sp >> 6, wo = sp & 63;
    const int ky = kk / 3, kx = kk - ky * 3;
    const float dy =
        ws[OF2 + ((batch * 18 + (kk << 1)) << 12) + sp] + bof[kk << 1];
    const float dx =
        ws[OF2 + ((batch * 18 + (kk << 1) + 1) << 12) + sp] + bof[(kk << 1) + 1];
    const float py = (float)(ho - 1 + ky) + dy;
    const float px = (float)(wo - 1 + kx) + dx;
    const float y0f = floorf(py), x0f = floorf(px);
    const float ly = py - y0f, lx = px - x0f;
    const int y0 = (int)y0f, x0 = (int)x0f;
    const int y1 = y0 + 1, x1 = x0 + 1;
    const float vy0 = (y0 >= 0 && y0 < 64) ? 1.f : 0.f;
    const float vy1 = (y1 >= 0 && y1 < 64) ? 1.f : 0.f;
    const float vx0 = (x0 >= 0 && x0 < 64) ? 1.f : 0.f;
    const float vx1 = (x1 >= 0 && x1 < 64) ? 1.f : 0.f;
    const int y0c = min(max(y0, 0), 63), y1c = min(max(y1, 0), 63);
    const int x0c = min(max(x0, 0), 63), x1c = min(max(x1, 0), 63);
    uint4 wv4;
    wv4.x = duph((1.f - ly) * (1.f - lx) * vy0 * vx0);
    wv4.y = duph((1.f - ly) * lx * vy0 * vx1);
    wv4.z = duph(ly * (1.f - lx) * vy1 * vx0);
    wv4.w = duph(ly * lx * vy1 * vx1);
    int4 pv;
    pv.x = (y0c << 6) + x0c;
    pv.y = (y0c << 6) + x1c;
    pv.z = (y1c << 6) + x0c;
    pv.w = (y1c << 6) + x1c;
    dW[u] = wv4;
    dP[u] = pv;
  }
  __syncthreads();

  f4 acc[4][2];
#pragma unroll
  for (int m = 0; m < 4; ++m)
#pragma unroll
    for (int nt = 0; nt < 2; ++nt) acc[m][nt] = f4{0.f, 0.f, 0.f, 0.f};

  uint4 cset0[4], cset1[4];
  uint4 w0v, w1v, wq; int4 pq;
  h8 aA[4][2], aN[4][2];
  int kkd, kkg, cwg, bufc;

#define FRDD(W_, P_, KK_) do { const int u_ = ((KK_) << 5) + sn;             \
    W_ = dW[u_]; P_ = dP[u_]; } while (0)

#define FGATH(DST_, P_) do {                                                 \
    const int co_ = (cwg << 5) + (cg8 << 2);                                 \
    DST_[0] = *(const uint4*)(xtu + ((P_).x << 7) + co_);                    \
    DST_[1] = *(const uint4*)(xtu + ((P_).y << 7) + co_);                    \
    DST_[2] = *(const uint4*)(xtu + ((P_).z << 7) + co_);                    \
    DST_[3] = *(const uint4*)(xtu + ((P_).w << 7) + co_);                    \
  } while (0)

#define FCOMB(CS_, WV_, BUF_) do {                                           \
    const h2 wc0_ = u2h2((WV_).x), wc1_ = u2h2((WV_).y);                     \
    const h2 wc2_ = u2h2((WV_).z), wc3_ = u2h2((WV_).w);                     \
    uint4 r_;                                                                \
    r_.x = h22u(u2h2(CS_[0].x) * wc0_ + u2h2(CS_[1].x) * wc1_ +              \
                u2h2(CS_[2].x) * wc2_ + u2h2(CS_[3].x) * wc3_);              \
    r_.y = h22u(u2h2(CS_[0].y) * wc0_ + u2h2(CS_[1].y) * wc1_ +              \
                u2h2(CS_[2].y) * wc2_ + u2h2(CS_[3].y) * wc3_);              \
    r_.z = h22u(u2h2(CS_[0].z) * wc0_ + u2h2(CS_[1].z) * wc1_ +              \
                u2h2(CS_[2].z) * wc2_ + u2h2(CS_[3].z) * wc3_);              \
    r_.w = h22u(u2h2(CS_[0].w) * wc0_ + u2h2(CS_[1].w) * wc1_ +              \
                u2h2(CS_[2].w) * wc2_ + u2h2(CS_[3].w) * wc3_);              \
    *(uint4*)&Bs[BUF_][sn][(cg8 ^ (sn & 7)) << 2] = r_;                      \
  } while (0)

#define FLOADA(I_, DST_) do {                                                \
    _Pragma("unroll")                                                        \
    for (int m = 0; m < 4; ++m)                                              \
      _Pragma("unroll")                                                      \
      for (int s = 0; s < 2; ++s) {                                          \
        const int f_ = ((I_) << 1) + s;                                      \
        DST_[m][s] = *(const h8*)(af +                                       \
            ((((f_ << 4) + (wv << 2) + m) << 6) + l) * 8);                   \
      }                                                                      \
  } while (0)

#define FMFMA(AC_, BUF_) do {                                                \
    h8 bB_[2][2];                                                            \
    _Pragma("unroll")                                                        \
    for (int nt = 0; nt < 2; ++nt)                                           \
      _Pragma("unroll")                                                      \
      for (int s = 0; s < 2; ++s) {                                          \
        const int snr_ = (nt << 4) + (l & 15);                               \
        const int ph_  = (((s << 2) + (l >> 4)) ^ (snr_ & 7)) << 2;          \
        bB_[nt][s] = *(const h8*)&Bs[BUF_][snr_][ph_];                       \
      }                                                                      \
    _Pragma("unroll")                                                        \
    for (int m = 0; m < 4; ++m)                                              \
      _Pragma("unroll")                                                      \
      for (int nt = 0; nt < 2; ++nt) {                                       \
        acc[m][nt] = __builtin_amdgcn_mfma_f32_16x16x32_f16(                 \
            AC_[m][0], bB_[nt][0], acc[m][nt], 0, 0, 0);                     \
        acc[m][nt] = __builtin_amdgcn_mfma_f32_16x16x32_f16(                 \
            AC_[m][1], bB_[nt][1], acc[m][nt], 0, 0, 0);                     \
      }                                                                      \
  } while (0)

#define FBODY(I_, AC_, AN_, CC_, WC_, CN_, WN_) do {                         \
    if ((I_) < 34) {                                                         \
      WN_ = wq; FGATH(CN_, pq);                                              \
      kkg++; if (kkg == 9) { kkg = 0; cwg++; }                               \
    }                                                                        \
    if ((I_) < 33) { FRDD(wq, pq, kkd); kkd = (kkd == 8) ? 0 : kkd + 1; }    \
    const int bufn_ = (bufc == 2) ? 0 : bufc + 1;                            \
    FMFMA(AC_, bufc);                                                        \
    if ((I_) < 35) {                                                         \
      FLOADA((I_) + 1, AN_);                                                 \
      FCOMB(CC_, WC_, bufn_);                                                \
    }                                                                        \
    bufc = bufn_;                                                            \
    __syncthreads();                                                         \
  } while (0)

  {
    uint4 wA; int4 pA;
    cwg = 0;
    FRDD(wA, pA, 0);
    FGATH(cset0, pA);
    FRDD(w1v, pA, 1);
    FGATH(cset1, pA);
    FRDD(wq, pq, 2);
    FLOADA(0, aA);
    FCOMB(cset0, wA, 0);
    kkd = 3; kkg = 2; bufc = 0;
  }
  __syncthreads();

  for (int i = 0; i < 36; i += 2) {
    FBODY(i,     aA, aN, cset1, w1v, cset0, w0v);
    FBODY(i + 1, aN, aA, cset0, w0v, cset1, w1v);
  }

  const float* bfold = ws + BF2;
  const int quad = l >> 4;
  const int ow = wv << 6;
#pragma unroll
  for (int m = 0; m < 4; ++m) {
    const int ob = ow + (m << 4) + (quad << 2);
    const f4 bf = *(const f4*)&bfold[ob];
#pragma unroll
    for (int nt = 0; nt < 2; ++nt) {
      const int sp = sp0 + (nt << 4) + (l & 15);
#pragma unroll
      for (int rr = 0; rr < 4; ++rr) {
        out[(((batch << 8) + ob + rr) << 12) + sp] =
            fmaxf(acc[m][nt][rr] + bf[rr], 0.f);
      }
    }
  }
}

// ---------------------------------------------------------------------------
extern "C" void kernel_launch(void* const* d_in, const int* in_sizes, int n_in,
                              void* d_out, int out_size, void* d_ws, size_t ws_size,
                              hipStream_t stream) {
  const float* x     = (const float*)d_in[0];
  const float* wof   = (const float*)d_in[1];
  const float* bof   = (const float*)d_in[2];
  const float* w     = (const float*)d_in[3];
  const float* bias  = (const float*)d_in[4];
  const float* gamma = (const float*)d_in[5];
  const float* beta  = (const float*)d_in[6];
  const float* mean  = (const float*)d_in[7];
  const float* var   = (const float*)d_in[8];
  float* out = (float*)d_out;
  float* ws  = (float*)d_ws;

  hipLaunchKernelGGL(prep0_k, dim3(288), dim3(256), 0, stream,
                     wof, bias, gamma, beta, mean, var, ws);
  hipLaunchKernelGGL(mid_k, dim3(3360), dim3(256), 0, stream,
                     x, w, gamma, var, ws);
  hipLaunchKernelGGL(deform_gemm_f16b, dim3(512), dim3(256), 0, stream,
                     ws, bof, out);
}